// Round 13
// baseline (392.583 us; speedup 1.0000x reference)
//
#include <hip/hip_runtime.h>

#define NT 32768
#define DM 1024
#define NTOT (NT + 128)          // 32896 = 257 * 128 ; 128-row gap separates experts

typedef __bf16 bf16x8 __attribute__((ext_vector_type(8)));
typedef float f32x4 __attribute__((ext_vector_type(4)));

// async global->LDS, 16B per lane; LDS dest is wave-uniform base + lane*16,
// global SOURCE is per-lane (m104/m108) -> gather-capable staging.
#define GLD16(g, l)                                                            \
  __builtin_amdgcn_global_load_lds(                                            \
      (const __attribute__((address_space(1))) void*)(g),                      \
      (__attribute__((address_space(3))) void*)(l), 16, 0, 0)

__device__ __forceinline__ unsigned short f2bf(float f) {
  unsigned u = __float_as_uint(f);
  u += 0x7fffu + ((u >> 16) & 1u);   // RNE
  return (unsigned short)(u >> 16);
}

// ------- fused prep: route (bid 0) | wt (1..2048) | cvt (2049..18432) -------
// ROUTE FIRST: the one serial block starts at t=0 and its ~10-15us latency
// hides under the cvt stream (R12 had it LAST -> naked serial tail after cvt
// drained). cvt stays straight-line 1 bf16x8/thread (TLP-hidden latency).
__global__ __launch_bounds__(256) void prep_k(
    const float* __restrict__ x, unsigned short* __restrict__ xb,
    const float* __restrict__ W1, const float* __restrict__ W2,
    unsigned short* __restrict__ Wt,
    const int* __restrict__ route, int* __restrict__ idx,
    int* __restrict__ counters) {
  __shared__ float tile[32][33];   // wt part
  __shared__ int wsum[4];          // route part
  const int bid = blockIdx.x;
  const int t = threadIdx.x;

  if (bid == 0) {
    // ---- route: 256 threads x 128 tokens, prefix-scan, zero atomics ----
    const int lane = t & 63, wv = t >> 6;
    const int base = t * 128;
    const int4* rp = (const int4*)(route + base);
    unsigned m[4] = {0u, 0u, 0u, 0u};
#pragma unroll
    for (int v = 0; v < 32; ++v) {
      int4 q = rp[v];
      const int g = v >> 3, sh = (v & 7) * 4;
      m[g] |= (unsigned)(q.x == 0) << (sh + 0);
      m[g] |= (unsigned)(q.y == 0) << (sh + 1);
      m[g] |= (unsigned)(q.z == 0) << (sh + 2);
      m[g] |= (unsigned)(q.w == 0) << (sh + 3);
    }
    const int c0 = __popc(m[0]) + __popc(m[1]) + __popc(m[2]) + __popc(m[3]);
    int s = c0;                                  // within-wave inclusive scan
#pragma unroll
    for (int d = 1; d < 64; d <<= 1) {
      int v = __shfl_up(s, (unsigned)d, 64);
      if (lane >= d) s += v;
    }
    if (lane == 63) wsum[wv] = s;
    __syncthreads();
    int waveBase = 0, total0 = 0;
#pragma unroll
    for (int w = 0; w < 4; ++w) {
      int v = wsum[w];
      if (w < wv) waveBase += v;
      total0 += v;
    }
    const int ex0 = waveBase + s - c0;           // excl. prefix of expert0 count
    int slot0 = ex0;
    int slot1 = NTOT - 1 - (base - ex0);
    for (int i = 0; i < 128; ++i) {
      int token = base + i;
      if ((m[i >> 5] >> (i & 31)) & 1) idx[slot0++] = token;
      else                             idx[slot1--] = token;
    }
    if (t == 0) { counters[0] = total0; counters[1] = NT - total0; }
  } else if (bid <= 2048) {
    // ---- wt: Wt[e][n][k] = bf16(W_e[k][n]) ----
    const int b = bid - 1;
    const int z = b >> 10;
    const int bb = b & 1023;
    const float* __restrict__ W = z ? W2 : W1;
    unsigned short* __restrict__ dst = Wt + (size_t)z * DM * DM;
    const int n0 = (bb & 31) * 32, k0 = (bb >> 5) * 32;
    const int tx = t & 31, ty = t >> 5;                // 32 x 8
#pragma unroll
    for (int i = 0; i < 32; i += 8)
      tile[ty + i][tx] = W[(size_t)(k0 + ty + i) * DM + n0 + tx];
    __syncthreads();
#pragma unroll
    for (int i = 0; i < 32; i += 8)
      dst[(size_t)(n0 + ty + i) * DM + k0 + tx] = f2bf(tile[tx][ty + i]);
  } else {
    // ---- cvt: xb = bf16(x), one bf16x8 unit per thread, straight-line ----
    const size_t p = (size_t)(bid - 2049) * 256 + t;   // 16384*256 == NT*DM/8
    float4 v0 = ((const float4*)x)[2 * p];
    float4 v1 = ((const float4*)x)[2 * p + 1];
    bf16x8 pk;                                         // casts -> v_cvt_pk_bf16_f32
    pk[0] = (__bf16)v0.x; pk[1] = (__bf16)v0.y;
    pk[2] = (__bf16)v0.z; pk[3] = (__bf16)v0.w;
    pk[4] = (__bf16)v1.x; pk[5] = (__bf16)v1.y;
    pk[6] = (__bf16)v1.z; pk[7] = (__bf16)v1.w;
    ((bf16x8*)xb)[p] = pk;
  }
}

// ------- grouped GEMM: R10 structure + 5 blk/CU (LDS 5x32K = 160K exactly) ---
// 128x128 tile, BK=64, 4 waves x (4x4) 16x16x32 MFMA, 32 KiB LDS.
// Occupancy is the proven dominant lever (R1->R5 monotone with blk/CU);
// VGPR 60 is far under the 5-waves/SIMD budget, LDS fits exactly.
// K-phase: panel-uniform stagger (desync barriers + A-panel L2 locality).
__global__ __launch_bounds__(256, 5) void gemm_k(
    const unsigned short* __restrict__ xb,    // [NT][DM] bf16, dense (token order)
    const unsigned short* __restrict__ Wt,    // [2][DM][DM] bf16, Wt[n][k]
    const float* __restrict__ b1, const float* __restrict__ b2,
    const int* __restrict__ idx, const int* __restrict__ counters,
    float* __restrict__ out) {
  __shared__ unsigned short As[128 * 64];   // swizzled [row][k-chunk]
  __shared__ unsigned short Bs[128 * 64];

  const int t = threadIdx.x;
  const int lane = t & 63, wave = t >> 6;

  // XCD-aware bijective swizzle: 2056 blocks = 8 XCDs x 257.
  const int lin = blockIdx.y * 8 + blockIdx.x;       // dispatch order, x fastest
  const int L = (lin & 7) * 257 + (lin >> 3);        // bijective since 2056 % 8 == 0
  const int row0 = (L >> 3) * 128;
  const int col0 = (L & 7) * 128;
  const int ph = (L >> 3) & 15;                      // panel-uniform stagger

  const int n0 = counters[0];
  const int expert = (row0 < n0) ? 0 : 1;   // 128-gap => tiles never mix experts
  const unsigned short* Wte = Wt + (size_t)expert * DM * DM;
  const float* bias = expert ? b2 : b1;

  const int wr = (wave >> 1) * 64;
  const int wc = (wave & 1) * 64;
  const int lr = lane & 15;

  // staging-gather prologue: thread t stages chunk q = p*256+t -> row
  // r = p*32 + (t>>3), swizzled chunk c = ((t&7) ^ ((t>>3)&7)) (thread-const).
  const int rsub = t >> 3;                       // 0..31
  const int cA = ((t & 7) ^ (rsub & 7)) * 8;     // swizzled element offset
  const unsigned short* aSrc[4];
  const unsigned short* bSrc[4];
#pragma unroll
  for (int p = 0; p < 4; ++p) {
    int gr = row0 + p * 32 + rsub;
    int tok = idx[gr];
    if (gr >= n0 && gr < n0 + 128) tok = 0;      // gap rows: valid dummy, discarded
    aSrc[p] = xb + (size_t)tok * DM + cA;
    bSrc[p] = Wte + (size_t)(col0 + p * 32 + rsub) * DM + cA;
  }

  f32x4 acc[4][4] = {};

  for (int kt = 0; kt < 16; ++kt) {
    const int k0 = ((kt + ph) & 15) * 64;        // circular K order
#pragma unroll
    for (int p = 0; p < 4; ++p) {
      int q = p * 256 + t;          // 1024 chunks of 16B per 128x64 tile
      GLD16(aSrc[p] + k0, As + q * 8);
      GLD16(bSrc[p] + k0, Bs + q * 8);
    }
    __syncthreads();
#pragma unroll
    for (int s = 0; s < 2; ++s) {
      const int cb = s * 4 + (lane >> 4);   // wanted 16B chunk within the row
      bf16x8 af[4], bfr[4];
#pragma unroll
      for (int i = 0; i < 4; ++i) {
        int r = wr + i * 16 + lr;
        af[i] = *(const bf16x8*)&As[(r * 8 + (cb ^ (r & 7))) * 8];
      }
#pragma unroll
      for (int j = 0; j < 4; ++j) {
        int r = wc + j * 16 + lr;
        bfr[j] = *(const bf16x8*)&Bs[(r * 8 + (cb ^ (r & 7))) * 8];
      }
#pragma unroll
      for (int i = 0; i < 4; ++i)
#pragma unroll
        for (int j = 0; j < 4; ++j)
          acc[i][j] = __builtin_amdgcn_mfma_f32_16x16x32_bf16(af[i], bfr[j], acc[i][j], 0, 0, 0);
    }
    __syncthreads();
  }

  // epilogue: scatter rows to original token positions, add bias (fp32).
  // gap rows [n0, n0+128) are discarded (their idx was never written).
#pragma unroll
  for (int i = 0; i < 4; ++i) {
#pragma unroll
    for (int reg = 0; reg < 4; ++reg) {
      int gr = row0 + wr + i * 16 + (lane >> 4) * 4 + reg;
      if (gr < n0 || gr >= n0 + 128) {
        int dest = idx[gr];
#pragma unroll
        for (int j = 0; j < 4; ++j) {
          int gc = col0 + wc + j * 16 + (lane & 15);
          out[(size_t)dest * DM + gc] = acc[i][j][reg] + bias[gc];
        }
      }
    }
  }
}

extern "C" void kernel_launch(void* const* d_in, const int* in_sizes, int n_in,
                              void* d_out, int out_size, void* d_ws, size_t ws_size,
                              hipStream_t stream) {
  const float* x   = (const float*)d_in[0];
  const float* W1  = (const float*)d_in[1];
  const float* b1  = (const float*)d_in[2];
  const float* W2  = (const float*)d_in[3];
  const float* b2  = (const float*)d_in[4];
  const int*   route = (const int*)d_in[5];
  float* out = (float*)d_out;

  char* ws = (char*)d_ws;
  unsigned short* xb = (unsigned short*)ws;                       // NT*DM bf16 (dense)
  size_t off = (size_t)NT * DM * 2;
  unsigned short* Wt = (unsigned short*)(ws + off);               // 2*DM*DM bf16
  off += (size_t)2 * DM * DM * 2;
  int* idx = (int*)(ws + off);                                    // NTOT ints
  int* counters = idx + NTOT;                                     // 2 ints

  prep_k<<<18433, 256, 0, stream>>>(x, xb, W1, W2, Wt, route, idx, counters);
  gemm_k<<<dim3(8, NTOT / 128), 256, 0, stream>>>(xb, Wt, b1, b2, idx, counters, out);
}

// Round 14
// 329.456 us; speedup vs baseline: 1.1916x; 1.1916x over previous
//
#include <hip/hip_runtime.h>

#define NT 32768
#define DM 1024
#define NTOT (NT + 128)          // 32896 = 257 * 128 ; 128-row gap separates experts

typedef __bf16 bf16x8 __attribute__((ext_vector_type(8)));
typedef float f32x4 __attribute__((ext_vector_type(4)));

// async global->LDS, 16B per lane; LDS dest is wave-uniform base + lane*16,
// global SOURCE is per-lane (m104/m108) -> gather-capable staging.
#define GLD16(g, l)                                                            \
  __builtin_amdgcn_global_load_lds(                                            \
      (const __attribute__((address_space(1))) void*)(g),                      \
      (__attribute__((address_space(3))) void*)(l), 16, 0, 0)

__device__ __forceinline__ unsigned short f2bf(float f) {
  unsigned u = __float_as_uint(f);
  u += 0x7fffu + ((u >> 16) & 1u);   // RNE
  return (unsigned short)(u >> 16);
}

// ------- fused prep: route (bid 0) | wt (1..2048) | cvt (2049..18432) -------
// Route-first: the serial route block's latency hides under the cvt stream
// (R13 attribution: prep 80 -> ~62us from this reorder alone).
__global__ __launch_bounds__(256) void prep_k(
    const float* __restrict__ x, unsigned short* __restrict__ xb,
    const float* __restrict__ W1, const float* __restrict__ W2,
    unsigned short* __restrict__ Wt,
    const int* __restrict__ route, int* __restrict__ idx,
    int* __restrict__ counters) {
  __shared__ float tile[32][33];   // wt part
  __shared__ int wsum[4];          // route part
  const int bid = blockIdx.x;
  const int t = threadIdx.x;

  if (bid == 0) {
    // ---- route: 256 threads x 128 tokens, prefix-scan, zero atomics ----
    const int lane = t & 63, wv = t >> 6;
    const int base = t * 128;
    const int4* rp = (const int4*)(route + base);
    unsigned m[4] = {0u, 0u, 0u, 0u};
#pragma unroll
    for (int v = 0; v < 32; ++v) {
      int4 q = rp[v];
      const int g = v >> 3, sh = (v & 7) * 4;
      m[g] |= (unsigned)(q.x == 0) << (sh + 0);
      m[g] |= (unsigned)(q.y == 0) << (sh + 1);
      m[g] |= (unsigned)(q.z == 0) << (sh + 2);
      m[g] |= (unsigned)(q.w == 0) << (sh + 3);
    }
    const int c0 = __popc(m[0]) + __popc(m[1]) + __popc(m[2]) + __popc(m[3]);
    int s = c0;                                  // within-wave inclusive scan
#pragma unroll
    for (int d = 1; d < 64; d <<= 1) {
      int v = __shfl_up(s, (unsigned)d, 64);
      if (lane >= d) s += v;
    }
    if (lane == 63) wsum[wv] = s;
    __syncthreads();
    int waveBase = 0, total0 = 0;
#pragma unroll
    for (int w = 0; w < 4; ++w) {
      int v = wsum[w];
      if (w < wv) waveBase += v;
      total0 += v;
    }
    const int ex0 = waveBase + s - c0;           // excl. prefix of expert0 count
    int slot0 = ex0;
    int slot1 = NTOT - 1 - (base - ex0);
    for (int i = 0; i < 128; ++i) {
      int token = base + i;
      if ((m[i >> 5] >> (i & 31)) & 1) idx[slot0++] = token;
      else                             idx[slot1--] = token;
    }
    if (t == 0) { counters[0] = total0; counters[1] = NT - total0; }
  } else if (bid <= 2048) {
    // ---- wt: Wt[e][n][k] = bf16(W_e[k][n]) ----
    const int b = bid - 1;
    const int z = b >> 10;
    const int bb = b & 1023;
    const float* __restrict__ W = z ? W2 : W1;
    unsigned short* __restrict__ dst = Wt + (size_t)z * DM * DM;
    const int n0 = (bb & 31) * 32, k0 = (bb >> 5) * 32;
    const int tx = t & 31, ty = t >> 5;                // 32 x 8
#pragma unroll
    for (int i = 0; i < 32; i += 8)
      tile[ty + i][tx] = W[(size_t)(k0 + ty + i) * DM + n0 + tx];
    __syncthreads();
#pragma unroll
    for (int i = 0; i < 32; i += 8)
      dst[(size_t)(n0 + ty + i) * DM + k0 + tx] = f2bf(tile[tx][ty + i]);
  } else {
    // ---- cvt: xb = bf16(x), one bf16x8 unit per thread, straight-line ----
    const size_t p = (size_t)(bid - 2049) * 256 + t;   // 16384*256 == NT*DM/8
    float4 v0 = ((const float4*)x)[2 * p];
    float4 v1 = ((const float4*)x)[2 * p + 1];
    bf16x8 pk;                                         // casts -> v_cvt_pk_bf16_f32
    pk[0] = (__bf16)v0.x; pk[1] = (__bf16)v0.y;
    pk[2] = (__bf16)v0.z; pk[3] = (__bf16)v0.w;
    pk[4] = (__bf16)v1.x; pk[5] = (__bf16)v1.y;
    pk[6] = (__bf16)v1.z; pk[7] = (__bf16)v1.w;
    ((bf16x8*)xb)[p] = pk;
  }
}

// ------- grouped GEMM: R10 structure exactly (4 blk/CU, VGPR 60, no spill) ---
// 128x128 tile, BK=64, 4 waves x (4x4) 16x16x32 MFMA, 32 KiB LDS, 4 blk/CU.
// R13 lesson: launch_bounds(256,5) starves the allocator below the 64 VGPRs
// acc[4][4] needs -> scratch spill (+27MB WRITE). Never bound below 4.
// K-phase: panel-uniform stagger (desync barriers + A-panel L2 locality).
__global__ __launch_bounds__(256, 4) void gemm_k(
    const unsigned short* __restrict__ xb,    // [NT][DM] bf16, dense (token order)
    const unsigned short* __restrict__ Wt,    // [2][DM][DM] bf16, Wt[n][k]
    const float* __restrict__ b1, const float* __restrict__ b2,
    const int* __restrict__ idx, const int* __restrict__ counters,
    float* __restrict__ out) {
  __shared__ unsigned short As[128 * 64];   // swizzled [row][k-chunk]
  __shared__ unsigned short Bs[128 * 64];

  const int t = threadIdx.x;
  const int lane = t & 63, wave = t >> 6;

  // XCD-aware bijective swizzle: 2056 blocks = 8 XCDs x 257.
  const int lin = blockIdx.y * 8 + blockIdx.x;       // dispatch order, x fastest
  const int L = (lin & 7) * 257 + (lin >> 3);        // bijective since 2056 % 8 == 0
  const int row0 = (L >> 3) * 128;
  const int col0 = (L & 7) * 128;
  const int ph = (L >> 3) & 15;                      // panel-uniform stagger

  const int n0 = counters[0];
  const int expert = (row0 < n0) ? 0 : 1;   // 128-gap => tiles never mix experts
  const unsigned short* Wte = Wt + (size_t)expert * DM * DM;
  const float* bias = expert ? b2 : b1;

  const int wr = (wave >> 1) * 64;
  const int wc = (wave & 1) * 64;
  const int lr = lane & 15;

  // staging-gather prologue: thread t stages chunk q = p*256+t -> row
  // r = p*32 + (t>>3), swizzled chunk c = ((t&7) ^ ((t>>3)&7)) (thread-const).
  const int rsub = t >> 3;                       // 0..31
  const int cA = ((t & 7) ^ (rsub & 7)) * 8;     // swizzled element offset
  const unsigned short* aSrc[4];
  const unsigned short* bSrc[4];
#pragma unroll
  for (int p = 0; p < 4; ++p) {
    int gr = row0 + p * 32 + rsub;
    int tok = idx[gr];
    if (gr >= n0 && gr < n0 + 128) tok = 0;      // gap rows: valid dummy, discarded
    aSrc[p] = xb + (size_t)tok * DM + cA;
    bSrc[p] = Wte + (size_t)(col0 + p * 32 + rsub) * DM + cA;
  }

  f32x4 acc[4][4] = {};

  for (int kt = 0; kt < 16; ++kt) {
    const int k0 = ((kt + ph) & 15) * 64;        // circular K order
#pragma unroll
    for (int p = 0; p < 4; ++p) {
      int q = p * 256 + t;          // 1024 chunks of 16B per 128x64 tile
      GLD16(aSrc[p] + k0, As + q * 8);
      GLD16(bSrc[p] + k0, Bs + q * 8);
    }
    __syncthreads();
#pragma unroll
    for (int s = 0; s < 2; ++s) {
      const int cb = s * 4 + (lane >> 4);   // wanted 16B chunk within the row
      bf16x8 af[4], bfr[4];
#pragma unroll
      for (int i = 0; i < 4; ++i) {
        int r = wr + i * 16 + lr;
        af[i] = *(const bf16x8*)&As[(r * 8 + (cb ^ (r & 7))) * 8];
      }
#pragma unroll
      for (int j = 0; j < 4; ++j) {
        int r = wc + j * 16 + lr;
        bfr[j] = *(const bf16x8*)&Bs[(r * 8 + (cb ^ (r & 7))) * 8];
      }
#pragma unroll
      for (int i = 0; i < 4; ++i)
#pragma unroll
        for (int j = 0; j < 4; ++j)
          acc[i][j] = __builtin_amdgcn_mfma_f32_16x16x32_bf16(af[i], bfr[j], acc[i][j], 0, 0, 0);
    }
    __syncthreads();
  }

  // epilogue: scatter rows to original token positions, add bias (fp32).
  // gap rows [n0, n0+128) are discarded (their idx was never written).
#pragma unroll
  for (int i = 0; i < 4; ++i) {
#pragma unroll
    for (int reg = 0; reg < 4; ++reg) {
      int gr = row0 + wr + i * 16 + (lane >> 4) * 4 + reg;
      if (gr < n0 || gr >= n0 + 128) {
        int dest = idx[gr];
#pragma unroll
        for (int j = 0; j < 4; ++j) {
          int gc = col0 + wc + j * 16 + (lane & 15);
          out[(size_t)dest * DM + gc] = acc[i][j][reg] + bias[gc];
        }
      }
    }
  }
}

extern "C" void kernel_launch(void* const* d_in, const int* in_sizes, int n_in,
                              void* d_out, int out_size, void* d_ws, size_t ws_size,
                              hipStream_t stream) {
  const float* x   = (const float*)d_in[0];
  const float* W1  = (const float*)d_in[1];
  const float* b1  = (const float*)d_in[2];
  const float* W2  = (const float*)d_in[3];
  const float* b2  = (const float*)d_in[4];
  const int*   route = (const int*)d_in[5];
  float* out = (float*)d_out;

  char* ws = (char*)d_ws;
  unsigned short* xb = (unsigned short*)ws;                       // NT*DM bf16 (dense)
  size_t off = (size_t)NT * DM * 2;
  unsigned short* Wt = (unsigned short*)(ws + off);               // 2*DM*DM bf16
  off += (size_t)2 * DM * DM * 2;
  int* idx = (int*)(ws + off);                                    // NTOT ints
  int* counters = idx + NTOT;                                     // 2 ints

  prep_k<<<18433, 256, 0, stream>>>(x, xb, W1, W2, Wt, route, idx, counters);
  gemm_k<<<dim3(8, NTOT / 128), 256, 0, stream>>>(xb, Wt, b1, b2, idx, counters, out);
}